// Round 4
// baseline (89.385 us; speedup 1.0000x reference)
//
#include <hip/hip_runtime.h>

// GaussianEdgeGuideV2: edge-guided 3x3 softmax filtering.
// mask: (8,64,128,128) fp32, edge: (8,1,64,64) fp32 -> out (8,64,128,128) fp32.
//
// R10 = R6 skeleton + per-wave CHANNEL ROTATION (single-mechanism probe).
// Evidence: kernel pinned at ~40-42us (dur 84.5-85.9 minus ~42.5us poison
// fill, geg always just under the top-5 fills) across depth-2/8, CG=4/8,
// split, LDS-staging variants. Little's law says bytes-in-flight are ample
// (96KB/CU vs ~9KB needed) -> not a simple MLP shortfall. New theory:
// WAVE LOCKSTEP. All 16 waves/CU run identical code on the SAME channel
// plane, released by the same barrier: loads burst, then all waves stall
// together on the same plane's first-touch misses (~900-1400cy under
// dirty-L2 evictions from the 256MiB fill). Effective MLP ~1 plane/block.
// R7's extra barriers tightened lockstep and regressed +16us -- consistent.
//
// Fix: weights are channel-independent, so channel ORDER is free. Wave w
// processes channels (2w+k)&7 -> 4 waves walk 4 different 64KB planes at
// any instant; miss streams de-correlate. Same loads/stores/instr count.
// Also: NT stores reverted to plain (R9: NT was -0..-1.4us vs R6 plain).
// Predict: lockstep right -> dur 85.9 -> ~66-75. Null (83-87) -> kernel is
// at an invisible floor; next round = duplicate-load traffic probe.

#define THETA 10.0f

constexpr int NB = 8;     // batch
constexpr int C  = 64;    // mask channels
constexpr int H  = 128, W = 128;
constexpr int EH = 64,  EW = 64;

constexpr int ROWS = 8;   // output rows per block tile
constexpr int CG   = 8;   // channels per block (C/CG = 8 groups)

// grid: x = C/CG = 8, y = H/ROWS = 16, z = NB = 8; block = 256
__global__ __launch_bounds__(256) void geg_kernel(
    const float* __restrict__ mask,
    const float* __restrict__ edge,
    float* __restrict__ out)
{
    // upsampled-edge tile with zero border (the unfold's zero padding)
    __shared__ float e_s[ROWS + 2][W + 4];   // fill/read cols 0..W+1

    const int t     = threadIdx.x;
    const int cg    = blockIdx.x;
    const int ytile = blockIdx.y;
    const int n     = blockIdx.z;
    const int y0    = ytile * ROWS;

    // ---- thread geometry: 4 consecutive-x pixels in one row
    const int lane = t & 31;         // position within the 32-lane row group
    const int x4   = lane * 4;       // 0,4,...,124
    const int r    = t >> 5;         // 0..7
    const int gy   = y0 + r;
    const int wid  = t >> 6;         // wave id 0..3: channel-rotation phase

    // clamped row offsets (OOB rows get zero weight; clamp keeps addr in-bounds)
    int rowoff[3];
    rowoff[0] = max(gy - 1, 0) * W + x4;
    rowoff[1] = gy * W + x4;
    rowoff[2] = min(gy + 1, H - 1) * W + x4;

    const int c0 = cg * CG;
    const float* mptr = mask + (size_t)(n * C + c0) * (H * W);

    // ---- issue first two rotated channels NOW; prologue hides their latency
    // wave w's channel sequence: ci = (2*wid + k) & 7, k = 0..7
    const int cbase = 2 * wid;
    float4 buf[2][3];
    #pragma unroll
    for (int i = 0; i < 3; ++i) {
        buf[0][i] = *(const float4*)(mptr + (cbase & 7) * (H * W) + rowoff[i]);
        buf[1][i] = *(const float4*)(mptr + ((cbase + 1) & 7) * (H * W) + rowoff[i]);
    }

    // ---- stage bilinear-upsampled edge rows [y0-1, y0+ROWS] x cols [-1, W]
    //      division-free mapping: 2 rows x 128 cols per step
    const float* eg = edge + n * (EH * EW);
    const float s = 63.0f / 127.0f;          // (EH-1)/(H-1)
    const int rr0 = t >> 7;                  // 0/1
    const int cc0 = t & 127;
    #pragma unroll
    for (int rb = 0; rb < ROWS + 2; rb += 2) {
        const int rr = rb + rr0;
        for (int cc = cc0; cc < W + 2; cc += 128) {
            int egy = y0 - 1 + rr;
            int egx = cc - 1;
            float v = 0.0f;
            if (egy >= 0 && egy < H && egx >= 0 && egx < W) {
                float ys = egy * s;
                float xs = egx * s;
                float yf = floorf(ys), xf = floorf(xs);
                int iy0 = (int)yf, ix0 = (int)xf;
                int iy1 = min(iy0 + 1, EH - 1), ix1 = min(ix0 + 1, EW - 1);
                float wy = ys - yf, wx = xs - xf;
                float tl = eg[iy0 * EW + ix0], tr = eg[iy0 * EW + ix1];
                float bl = eg[iy1 * EW + ix0], br = eg[iy1 * EW + ix1];
                float lv = tl + (bl - tl) * wy;
                float rv = tr + (br - tr) * wy;
                v = lv + (rv - lv) * wx;
            }
            e_s[rr][cc] = v;
        }
    }
    __syncthreads();

    // ---- per-pixel softmax weights (OOB neighbors zeroed; denom keeps all 9)
    //      NOTE: channel-independent -> valid for any channel order.
    float w[4][9];
    #pragma unroll
    for (int p = 0; p < 4; ++p) {
        const int gx = x4 + p;
        const float c = e_s[r + 1][gx + 1];
        float a[9], sum = 0.0f;
        #pragma unroll
        for (int di = 0; di < 3; ++di) {
            #pragma unroll
            for (int dj = 0; dj < 3; ++dj) {
                float d = c - e_s[r + di][gx + dj];
                float e = __expf(-THETA * d * d);
                a[di * 3 + dj] = e;
                sum += e;
            }
        }
        const float inv = 1.0f / sum;
        #pragma unroll
        for (int di = 0; di < 3; ++di) {
            #pragma unroll
            for (int dj = 0; dj < 3; ++dj) {
                int ny = gy + di - 1, nx = gx + dj - 1;
                bool ok = (ny >= 0) & (ny < H) & (nx >= 0) & (nx < W);
                w[p][di * 3 + dj] = ok ? a[di * 3 + dj] * inv : 0.0f;
            }
        }
    }

    // ---- channel loop, depth-2 prefetch, per-wave rotated channel order
    float* optr = out + (size_t)(n * C + c0) * (H * W) + gy * W + x4;

    #pragma unroll
    for (int k = 0; k < CG; ++k) {
        const int ci = (cbase + k) & 7;

        float4 cur[3];
        #pragma unroll
        for (int i = 0; i < 3; ++i) cur[i] = buf[k & 1][i];

        if (k + 2 < CG) {
            const int cp = (cbase + k + 2) & 7;
            #pragma unroll
            for (int i = 0; i < 3; ++i)
                buf[k & 1][i] = *(const float4*)(mptr + cp * (H * W) + rowoff[i]);
        }

        float av[4] = {0.f, 0.f, 0.f, 0.f};
        #pragma unroll
        for (int i = 0; i < 3; ++i) {
            // 6-wide row window; x-halo via shuffle in the 32-lane row group
            // (edge lanes get junk, but their weight is 0)
            float m6[6];
            m6[0] = __shfl_up(cur[i].w, 1, 32);
            m6[1] = cur[i].x; m6[2] = cur[i].y; m6[3] = cur[i].z; m6[4] = cur[i].w;
            m6[5] = __shfl_down(cur[i].x, 1, 32);
            #pragma unroll
            for (int p = 0; p < 4; ++p) {
                av[p] = fmaf(m6[p + 0], w[p][i * 3 + 0],
                        fmaf(m6[p + 1], w[p][i * 3 + 1],
                        fmaf(m6[p + 2], w[p][i * 3 + 2], av[p])));
            }
        }
        *(float4*)(optr + ci * (H * W)) = make_float4(av[0], av[1], av[2], av[3]);
    }
}

extern "C" void kernel_launch(void* const* d_in, const int* in_sizes, int n_in,
                              void* d_out, int out_size, void* d_ws, size_t ws_size,
                              hipStream_t stream) {
    const float* mask = (const float*)d_in[0];
    const float* edge = (const float*)d_in[1];
    float* out = (float*)d_out;

    dim3 grid(C / CG, H / ROWS, NB);   // 8 x 16 x 8 = 1024 blocks
    dim3 block(256);
    geg_kernel<<<grid, block, 0, stream>>>(mask, edge, out);
}

// Round 5
// 86.889 us; speedup vs baseline: 1.0287x; 1.0287x over previous
//
#include <hip/hip_runtime.h>

// GaussianEdgeGuideV2: edge-guided 3x3 softmax filtering.
// mask: (8,64,128,128) fp32, edge: (8,1,64,64) fp32 -> out (8,64,128,128) fp32.
//
// R11 = occupancy doubling via 2px/thread (VGPR<=64 -> 8 waves/SIMD).
// Ledger: R6 84.5 / R7-LDS 101.4 / R9 85.9 / R10-rotate 89.4. R7's +17us
// with its kernel still <43us (absent from top-5) bounds kernel_R6 < 26us;
// fixed harness cost >= 58us. Kernel ~2x over the ~12us BW floor.
// Theory: the 4px x 8ch decomposition fixes total waves at 4096 = 4/SIMD;
// depth-2 prefetch covers ~350cy of ~900cy HBM latency, and 4 waves/SIMD
// can't hide the rest. R5b's "CG=4 TLP null" never raised occupancy (kept
// ~100 VGPR -> still 4 resident waves/SIMD) so TLP is actually UNTESTED.
// Change: 2px/thread, float2 path, w[2][9], buf[2][3]f2 (~55 VGPR est),
// __launch_bounds__(256,8); ROWS=4, grid 8x32x8=2048 blocks -> 32 waves/CU.
// Same per-pixel weight math (no prologue duplication). Shuffle halo now
// width-64 (full wave); edge lanes masked by zero weights as before.
// Predict: TLP binding -> kernel ~24->14-16, dur 85.9 -> ~74-78.
//          Spills -> >=95 (check scratch). Null ~84-86 -> declare floor.

#define THETA 10.0f

constexpr int NB = 8;     // batch
constexpr int C  = 64;    // mask channels
constexpr int H  = 128, W = 128;
constexpr int EH = 64,  EW = 64;
constexpr int HW = H * W;

constexpr int ROWS = 4;   // output rows per block tile
constexpr int CG   = 8;   // channels per block (C/CG = 8 groups)

// grid: x = C/CG = 8, y = H/ROWS = 32, z = NB = 8; block = 256 (4 waves)
__global__ __launch_bounds__(256, 8) void geg_kernel(
    const float* __restrict__ mask,
    const float* __restrict__ edge,
    float* __restrict__ out)
{
    // upsampled-edge tile with zero border (the unfold's zero padding)
    __shared__ float e_s[ROWS + 2][W + 4];   // fill/read cols 0..W+1

    const int t     = threadIdx.x;
    const int cg    = blockIdx.x;
    const int ytile = blockIdx.y;
    const int n     = blockIdx.z;
    const int y0    = ytile * ROWS;

    // ---- thread geometry: 2 consecutive-x pixels in one row
    //      one row of 128 px = 64 lanes x 2px = one full wave
    const int lane = t & 63;         // lane within the wave-row
    const int x2   = lane * 2;       // 0,2,...,126
    const int r    = t >> 6;         // 0..3
    const int gy   = y0 + r;

    // clamped row offsets (OOB rows get zero weight; clamp keeps addr in-bounds)
    int rowoff[3];
    rowoff[0] = max(gy - 1, 0) * W + x2;
    rowoff[1] = gy * W + x2;
    rowoff[2] = min(gy + 1, H - 1) * W + x2;

    const int c0 = cg * CG;
    const float* mptr = mask + (size_t)(n * C + c0) * HW;

    // ---- issue ch0+ch1 loads NOW; the prologue below hides their latency
    float2 buf[2][3];
    #pragma unroll
    for (int i = 0; i < 3; ++i) {
        buf[0][i] = *(const float2*)(mptr + rowoff[i]);
        buf[1][i] = *(const float2*)(mptr + HW + rowoff[i]);
    }

    // ---- stage bilinear-upsampled edge rows [y0-1, y0+ROWS] x cols [-1, W]
    //      division-free mapping: 2 rows x 128 cols per step
    const float* eg = edge + n * (EH * EW);
    const float s = 63.0f / 127.0f;          // (EH-1)/(H-1)
    const int rr0 = t >> 7;                  // 0/1
    const int cc0 = t & 127;
    #pragma unroll
    for (int rb = 0; rb < ROWS + 2; rb += 2) {
        const int rr = rb + rr0;
        for (int cc = cc0; cc < W + 2; cc += 128) {
            int egy = y0 - 1 + rr;
            int egx = cc - 1;
            float v = 0.0f;
            if (egy >= 0 && egy < H && egx >= 0 && egx < W) {
                float ys = egy * s;
                float xs = egx * s;
                float yf = floorf(ys), xf = floorf(xs);
                int iy0 = (int)yf, ix0 = (int)xf;
                int iy1 = min(iy0 + 1, EH - 1), ix1 = min(ix0 + 1, EW - 1);
                float wy = ys - yf, wx = xs - xf;
                float tl = eg[iy0 * EW + ix0], tr = eg[iy0 * EW + ix1];
                float bl = eg[iy1 * EW + ix0], br = eg[iy1 * EW + ix1];
                float lv = tl + (bl - tl) * wy;
                float rv = tr + (br - tr) * wy;
                v = lv + (rv - lv) * wx;
            }
            e_s[rr][cc] = v;
        }
    }
    __syncthreads();

    // ---- per-pixel softmax weights (OOB neighbors zeroed; denom keeps all 9)
    float w[2][9];
    #pragma unroll
    for (int p = 0; p < 2; ++p) {
        const int gx = x2 + p;
        const float c = e_s[r + 1][gx + 1];
        float a[9], sum = 0.0f;
        #pragma unroll
        for (int di = 0; di < 3; ++di) {
            #pragma unroll
            for (int dj = 0; dj < 3; ++dj) {
                float d = c - e_s[r + di][gx + dj];
                float e = __expf(-THETA * d * d);
                a[di * 3 + dj] = e;
                sum += e;
            }
        }
        const float inv = 1.0f / sum;
        #pragma unroll
        for (int di = 0; di < 3; ++di) {
            #pragma unroll
            for (int dj = 0; dj < 3; ++dj) {
                int ny = gy + di - 1, nx = gx + dj - 1;
                bool ok = (ny >= 0) & (ny < H) & (nx >= 0) & (nx < W);
                w[p][di * 3 + dj] = ok ? a[di * 3 + dj] * inv : 0.0f;
            }
        }
    }

    // ---- channel loop, depth-2 prefetch
    float* optr = out + (size_t)(n * C + c0) * HW + gy * W + x2;

    #pragma unroll
    for (int ci = 0; ci < CG; ++ci) {
        float2 cur[3];
        #pragma unroll
        for (int i = 0; i < 3; ++i) cur[i] = buf[ci & 1][i];

        if (ci + 2 < CG) {
            #pragma unroll
            for (int i = 0; i < 3; ++i)
                buf[ci & 1][i] = *(const float2*)(mptr + (ci + 2) * HW + rowoff[i]);
        }

        float av[2] = {0.f, 0.f};
        #pragma unroll
        for (int i = 0; i < 3; ++i) {
            // 4-wide row window [x2-1, x2+2]; x-halo via full-wave shuffles
            // (edge lanes get junk, but their weight is 0)
            float m4[4];
            m4[0] = __shfl_up(cur[i].y, 1);
            m4[1] = cur[i].x; m4[2] = cur[i].y;
            m4[3] = __shfl_down(cur[i].x, 1);
            #pragma unroll
            for (int p = 0; p < 2; ++p) {
                av[p] = fmaf(m4[p + 0], w[p][i * 3 + 0],
                        fmaf(m4[p + 1], w[p][i * 3 + 1],
                        fmaf(m4[p + 2], w[p][i * 3 + 2], av[p])));
            }
        }
        *(float2*)(optr + ci * HW) = make_float2(av[0], av[1]);
    }
}

extern "C" void kernel_launch(void* const* d_in, const int* in_sizes, int n_in,
                              void* d_out, int out_size, void* d_ws, size_t ws_size,
                              hipStream_t stream) {
    const float* mask = (const float*)d_in[0];
    const float* edge = (const float*)d_in[1];
    float* out = (float*)d_out;

    dim3 grid(C / CG, H / ROWS, NB);   // 8 x 32 x 8 = 2048 blocks
    dim3 block(256);
    geg_kernel<<<grid, block, 0, stream>>>(mask, edge, out);
}

// Round 6
// 84.915 us; speedup vs baseline: 1.0526x; 1.0232x over previous
//
#include <hip/hip_runtime.h>

// GaussianEdgeGuideV2: edge-guided 3x3 softmax filtering.
// mask: (8,64,128,128) fp32, edge: (8,1,64,64) fp32 -> out (8,64,128,128) fp32.
//
// R12 = exact revert to R6, the measured session best (84.5us).
// Ledger: R6 84.5 / R7-LDS 101.4 / R9 +NT/divfree 85.9 / R10 +rotation 89.4
// / R11 2px-8waves 86.9. Six structural probes (deep prefetch, split, LDS
// staging, channel rotation, 2x occupancy) all null-or-negative around a
// 84.5-86.9 plateau -> kernel is NOT latency-, occupancy-, or
// ordering-bound. Revised floor model: the 256MiB ws poison leaves L2
// fully dirty, so the kernel pays ~33.5MB read + 33.5MB write + ~30MB
// dirty write-back ~= 100MB HBM => ~16us conditioned floor + ~2-3us VALU.
// dur 84.5 ~= fixed harness ~66 (fill 42.5 + poisons + launch) + kernel
// ~18 -> R6 already sits within ~10-20% of its achievable floor, which is
// why every "fix" regressed. Final answer: the R6 structure, unmodified.
// Predict: dur ~84.5 +- 1.5, absmax 0.0078125.

#define THETA 10.0f

constexpr int NB = 8;     // batch
constexpr int C  = 64;    // mask channels
constexpr int H  = 128, W = 128;
constexpr int EH = 64,  EW = 64;

constexpr int ROWS = 8;   // output rows per block tile
constexpr int CG   = 8;   // channels per block (C/CG = 8 groups)

// grid: x = C/CG = 8, y = H/ROWS = 16, z = NB = 8; block = 256
__global__ __launch_bounds__(256) void geg_kernel(
    const float* __restrict__ mask,
    const float* __restrict__ edge,
    float* __restrict__ out)
{
    // upsampled-edge tile with zero border (the unfold's zero padding)
    __shared__ float e_s[ROWS + 2][W + 4];   // fill/read cols 0..W+1

    const int t     = threadIdx.x;
    const int cg    = blockIdx.x;
    const int ytile = blockIdx.y;
    const int n     = blockIdx.z;
    const int y0    = ytile * ROWS;

    // ---- thread geometry: 4 consecutive-x pixels in one row
    const int lane = t & 31;         // position within the 32-lane row group
    const int x4   = lane * 4;       // 0,4,...,124
    const int r    = t >> 5;         // 0..7
    const int gy   = y0 + r;

    // clamped row offsets (OOB rows get zero weight; clamp keeps addr in-bounds)
    int rowoff[3];
    rowoff[0] = max(gy - 1, 0) * W + x4;
    rowoff[1] = gy * W + x4;
    rowoff[2] = min(gy + 1, H - 1) * W + x4;

    const int c0 = cg * CG;
    const float* mptr = mask + (size_t)(n * C + c0) * (H * W);

    // ---- issue ch0+ch1 loads NOW; the prologue below hides their latency
    float4 buf[2][3];
    #pragma unroll
    for (int i = 0; i < 3; ++i) {
        buf[0][i] = *(const float4*)(mptr + rowoff[i]);
        buf[1][i] = *(const float4*)(mptr + H * W + rowoff[i]);
    }

    // ---- stage bilinear-upsampled edge rows [y0-1, y0+ROWS] x cols [-1, W]
    const float* eg = edge + n * (EH * EW);
    const float s = 63.0f / 127.0f;          // (EH-1)/(H-1)
    for (int idx = t; idx < (ROWS + 2) * (W + 2); idx += 256) {
        int rr = idx / (W + 2);
        int cc = idx - rr * (W + 2);
        int egy = y0 - 1 + rr;
        int egx = cc - 1;
        float v = 0.0f;
        if (egy >= 0 && egy < H && egx >= 0 && egx < W) {
            float ys = egy * s;
            float xs = egx * s;
            float yf = floorf(ys), xf = floorf(xs);
            int iy0 = (int)yf, ix0 = (int)xf;
            int iy1 = min(iy0 + 1, EH - 1), ix1 = min(ix0 + 1, EW - 1);
            float wy = ys - yf, wx = xs - xf;
            float tl = eg[iy0 * EW + ix0], tr = eg[iy0 * EW + ix1];
            float bl = eg[iy1 * EW + ix0], br = eg[iy1 * EW + ix1];
            float lv = tl + (bl - tl) * wy;
            float rv = tr + (br - tr) * wy;
            v = lv + (rv - lv) * wx;
        }
        e_s[rr][cc] = v;
    }
    __syncthreads();

    // ---- per-pixel softmax weights (OOB neighbors zeroed; denom keeps all 9)
    float w[4][9];
    #pragma unroll
    for (int p = 0; p < 4; ++p) {
        const int gx = x4 + p;
        const float c = e_s[r + 1][gx + 1];
        float a[9], sum = 0.0f;
        #pragma unroll
        for (int di = 0; di < 3; ++di) {
            #pragma unroll
            for (int dj = 0; dj < 3; ++dj) {
                float d = c - e_s[r + di][gx + dj];
                float e = __expf(-THETA * d * d);
                a[di * 3 + dj] = e;
                sum += e;
            }
        }
        const float inv = 1.0f / sum;
        #pragma unroll
        for (int di = 0; di < 3; ++di) {
            #pragma unroll
            for (int dj = 0; dj < 3; ++dj) {
                int ny = gy + di - 1, nx = gx + dj - 1;
                bool ok = (ny >= 0) & (ny < H) & (nx >= 0) & (nx < W);
                w[p][di * 3 + dj] = ok ? a[di * 3 + dj] * inv : 0.0f;
            }
        }
    }

    // ---- channel loop, depth-2 prefetch
    float* optr = out + (size_t)(n * C + c0) * (H * W) + gy * W + x4;

    #pragma unroll
    for (int ci = 0; ci < CG; ++ci) {
        float4 cur[3];
        #pragma unroll
        for (int i = 0; i < 3; ++i) cur[i] = buf[ci & 1][i];

        if (ci + 2 < CG) {
            #pragma unroll
            for (int i = 0; i < 3; ++i)
                buf[ci & 1][i] = *(const float4*)(mptr + (ci + 2) * (H * W) + rowoff[i]);
        }

        float av[4] = {0.f, 0.f, 0.f, 0.f};
        #pragma unroll
        for (int i = 0; i < 3; ++i) {
            // 6-wide row window; x-halo via shuffle in the 32-lane row group
            // (edge lanes get junk, but their weight is 0)
            float m6[6];
            m6[0] = __shfl_up(cur[i].w, 1, 32);
            m6[1] = cur[i].x; m6[2] = cur[i].y; m6[3] = cur[i].z; m6[4] = cur[i].w;
            m6[5] = __shfl_down(cur[i].x, 1, 32);
            #pragma unroll
            for (int p = 0; p < 4; ++p) {
                av[p] = fmaf(m6[p + 0], w[p][i * 3 + 0],
                        fmaf(m6[p + 1], w[p][i * 3 + 1],
                        fmaf(m6[p + 2], w[p][i * 3 + 2], av[p])));
            }
        }
        *(float4*)(optr + ci * (H * W)) = make_float4(av[0], av[1], av[2], av[3]);
    }
}

extern "C" void kernel_launch(void* const* d_in, const int* in_sizes, int n_in,
                              void* d_out, int out_size, void* d_ws, size_t ws_size,
                              hipStream_t stream) {
    const float* mask = (const float*)d_in[0];
    const float* edge = (const float*)d_in[1];
    float* out = (float*)d_out;

    dim3 grid(C / CG, H / ROWS, NB);   // 8 x 16 x 8 = 1024 blocks
    dim3 block(256);
    geg_kernel<<<grid, block, 0, stream>>>(mask, edge, out);
}